// Round 11
// baseline (447.061 us; speedup 1.0000x reference)
//
#include <hip/hip_runtime.h>
#include <hip/hip_fp16.h>

#define RES 512
#define NCH 32
#define HW (RES * RES)
#define PLANE_H_ELEMS (NCH * HW)     // half elements per transposed plane
#define NBUCKETS 4096                // 16x16x16 Morton voxel grid

typedef float vfloat4 __attribute__((ext_vector_type(4)));  // proven for NT STORE only

// ---------------------------------------------------------------------------
// Morton bucket helpers
// ---------------------------------------------------------------------------
__device__ __forceinline__ unsigned spread3(unsigned x) {
    x &= 0x3FF;
    x = (x | (x << 16)) & 0x030000FF;
    x = (x | (x <<  8)) & 0x0300F00F;
    x = (x | (x <<  4)) & 0x030C30C3;
    x = (x | (x <<  2)) & 0x09249249;
    return x;
}
__device__ __forceinline__ unsigned bucket_of(float c0, float c1, float c2) {
    int bx = min(max((int)(c0 * 16.f), 0), 15);
    int by = min(max((int)(c1 * 16.f), 0), 15);
    int bz = min(max((int)(c2 * 16.f), 0), 15);
    return spread3(bx) | (spread3(by) << 1) | (spread3(bz) << 2);
}

// ---------------------------------------------------------------------------
// Tiny zero kernel for the histogram (must precede the fused kernel's
// hist atomics; separate node guarantees ordering).
// ---------------------------------------------------------------------------
__global__ __launch_bounds__(256) void zero_hist(unsigned* __restrict__ hist) {
    hist[blockIdx.x * 256 + threadIdx.x] = 0u;
}

// ---------------------------------------------------------------------------
// Fused pre-pass: blocks 0..1023 build the point histogram (dispatched FIRST
// so they overlap the transpose flood); blocks 1024..13311 transpose
// (C,H,W) fp32 -> (H,W,C) fp16 (verbatim r10 transpose logic).
// ---------------------------------------------------------------------------
#define HIST_BLOCKS 1024
__global__ __launch_bounds__(256) void fused_transpose_hist(
    const float* __restrict__ p0, const float* __restrict__ p1,
    const float* __restrict__ p2, __half2* __restrict__ dst_all,
    const float* __restrict__ x, int npts, unsigned* __restrict__ hist)
{
    __shared__ char smem[16384];
    int blk = blockIdx.x;
    int t   = threadIdx.x;

    if (blk < HIST_BLOCKS) {
        // ---- histogram path (r10 hist_kernel body, 1024 slices) ----
        unsigned* lh = (unsigned*)smem;
        for (int i = t; i < NBUCKETS; i += 256) lh[i] = 0;
        __syncthreads();
        int per = (npts + HIST_BLOCKS - 1) / HIST_BLOCKS;
        int start = blk * per;
        int end = min(npts, start + per);
        for (int i = start + t; i < end; i += 256) {
            float c0 = x[3 * i + 0], c1 = x[3 * i + 1], c2 = x[3 * i + 2];
            atomicAdd(&lh[bucket_of(c0, c1, c2)], 1u);
        }
        __syncthreads();
        for (int i = t; i < NBUCKETS; i += 256)
            if (lh[i]) atomicAdd(&hist[i], lh[i]);
        return;
    }

    // ---- transpose path ----
    float* lds = (float*)smem;            // 64*33*4 = 8448 B < 16384
    int tblk  = blk - HIST_BLOCKS;
    int plane = tblk >> 12;
    int rem   = tblk & 4095;
    int y     = rem >> 3;
    int xt    = (rem & 7) << 6;
    const float* src = (plane == 0) ? p0 : (plane == 1) ? p1 : p2;
    __half2* dst = dst_all + (size_t)plane * (PLANE_H_ELEMS / 2);

    #pragma unroll
    for (int k = 0; k < 8; ++k) {
        int idx = t + (k << 8);      // 0..2047
        int c   = idx >> 6;          // channel 0..31
        int xi  = idx & 63;          // x within tile
        lds[xi * 33 + c] = src[(size_t)c * HW + (size_t)y * RES + xt + xi];
    }
    __syncthreads();
    #pragma unroll
    for (int k = 0; k < 4; ++k) {
        int idx = t + (k << 8);      // 0..1023
        int xi  = idx >> 4;          // x within tile
        int cp  = idx & 15;          // channel pair
        __half2 h = __halves2half2(__float2half_rn(lds[xi * 33 + 2 * cp]),
                                   __float2half_rn(lds[xi * 33 + 2 * cp + 1]));
        dst[((size_t)(y * RES + xt + xi)) * 16 + cp] = h;
    }
}

// ---------------------------------------------------------------------------
// Counting sort pass 2: exclusive scan of 4096 counts. One block, 1024 thr.
// ---------------------------------------------------------------------------
__global__ __launch_bounds__(1024) void scan_kernel(
    const unsigned* __restrict__ hist, unsigned* __restrict__ offs)
{
    __shared__ unsigned sd[1024];
    int t = threadIdx.x;
    unsigned h0 = hist[4 * t + 0], h1 = hist[4 * t + 1];
    unsigned h2 = hist[4 * t + 2], h3 = hist[4 * t + 3];
    sd[t] = h0 + h1 + h2 + h3;
    __syncthreads();
    for (int d = 1; d < 1024; d <<= 1) {
        unsigned v = (t >= d) ? sd[t - d] : 0u;
        __syncthreads();
        sd[t] += v;
        __syncthreads();
    }
    unsigned excl = (t > 0) ? sd[t - 1] : 0u;
    offs[4 * t + 0] = excl;
    offs[4 * t + 1] = excl + h0;
    offs[4 * t + 2] = excl + h0 + h1;
    offs[4 * t + 3] = excl + h0 + h1 + h2;
}

// ---------------------------------------------------------------------------
// Counting sort pass 3: scatter (c0,c1,c2,orig_idx) into bucket order.
// ---------------------------------------------------------------------------
__global__ __launch_bounds__(256) void scatter_kernel(
    const float* __restrict__ x, int npts, unsigned* __restrict__ offs,
    float4* __restrict__ sorted)
{
    int i = blockIdx.x * 256 + threadIdx.x;
    if (i >= npts) return;
    float c0 = x[3 * i + 0], c1 = x[3 * i + 1], c2 = x[3 * i + 2];
    unsigned b = bucket_of(c0, c1, c2);
    unsigned pos = atomicAdd(&offs[b], 1u);
    sorted[pos] = make_float4(c0, c1, c2, __int_as_float(i));
}

// ---------------------------------------------------------------------------
// fp16-pair decode + bilinear accumulate helper (proven math path).
// ---------------------------------------------------------------------------
__device__ __forceinline__ float2 dec2(unsigned u) {
    return __half22float2(__builtin_bit_cast(__half2, u));
}
__device__ __forceinline__ void bilerp2(float2& acc, unsigned c00, unsigned c01,
                                        unsigned c10, unsigned c11,
                                        float w00, float w01, float w10, float w11) {
    float2 a = dec2(c00), b = dec2(c01), c = dec2(c10), d = dec2(c11);
    float f0 = fmaf(a.x, w00, fmaf(b.x, w01, fmaf(c.x, w10, d.x * w11)));
    float f1 = fmaf(a.y, w00, fmaf(b.y, w01, fmaf(c.y, w10, d.y * w11)));
    acc.x *= f0; acc.y *= f1;
}

// ---------------------------------------------------------------------------
// Sampler body (verbatim r10 logic), parameterized so the production kernel
// and the diagnostic probe share identical code.
// ---------------------------------------------------------------------------
__device__ __forceinline__ void sample_body(
    const float4* __restrict__ sorted, const __half* __restrict__ planes,
    float* __restrict__ out, int npts, int nb_q, int nb_r,
    int bid, int tid)
{
    int xcd = bid & 7;
    int j   = bid >> 3;
    int chunk = (xcd < nb_r ? xcd * (nb_q + 1) : nb_r * (nb_q + 1) + (xcd - nb_r) * nb_q) + j;

    int s = chunk * 64 + (tid >> 2);           // 64 points per block
    int q = tid & 3;                           // channel octet
    if (s >= npts) return;

    float4 p = sorted[s];
    int b = __float_as_int(p.w);               // original point index

    const float gxs[3] = { p.x, p.x, p.y };
    const float gys[3] = { p.y, p.z, p.z };

    const __half* base[3];
    float w00[3], w01[3], w10[3], w11[3];
    #pragma unroll
    for (int pl = 0; pl < 3; ++pl) {
        float ix = fmaf(gxs[pl], 255.5f, 255.5f);
        float iy = fmaf(gys[pl], 255.5f, 255.5f);
        float xf = floorf(ix), yf = floorf(iy);
        float wx = ix - xf,  wy = iy - yf;
        int x0 = min(max((int)xf, 0), RES - 2);
        int y0 = min(max((int)yf, 0), RES - 2);
        base[pl] = planes + (size_t)pl * PLANE_H_ELEMS
                 + (size_t)(y0 * RES + x0) * NCH + q * 8;
        float omx = 1.f - wx, omy = 1.f - wy;
        w00[pl] = omx * omy; w01[pl] = wx * omy;
        w10[pl] = omx * wy;  w11[pl] = wx * wy;
    }

    uint4 u00[3], u01[3], u10[3], u11[3];
    #pragma unroll
    for (int pl = 0; pl < 3; ++pl) {
        u00[pl] = *(const uint4*)(base[pl]);
        u01[pl] = *(const uint4*)(base[pl] + NCH);
        u10[pl] = *(const uint4*)(base[pl] + RES * NCH);
        u11[pl] = *(const uint4*)(base[pl] + RES * NCH + NCH);
    }

    float2 acc0 = {1.f, 1.f}, acc1 = {1.f, 1.f}, acc2 = {1.f, 1.f}, acc3 = {1.f, 1.f};
    #pragma unroll
    for (int pl = 0; pl < 3; ++pl) {
        bilerp2(acc0, u00[pl].x, u01[pl].x, u10[pl].x, u11[pl].x,
                w00[pl], w01[pl], w10[pl], w11[pl]);
        bilerp2(acc1, u00[pl].y, u01[pl].y, u10[pl].y, u11[pl].y,
                w00[pl], w01[pl], w10[pl], w11[pl]);
        bilerp2(acc2, u00[pl].z, u01[pl].z, u10[pl].z, u11[pl].z,
                w00[pl], w01[pl], w10[pl], w11[pl]);
        bilerp2(acc3, u00[pl].w, u01[pl].w, u10[pl].w, u11[pl].w,
                w00[pl], w01[pl], w10[pl], w11[pl]);
    }

    float* op = out + (size_t)b * NCH + q * 8;
    vfloat4 lo = { acc0.x, acc0.y, acc1.x, acc1.y };
    vfloat4 hi = { acc2.x, acc2.y, acc3.x, acc3.y };
    __builtin_nontemporal_store(lo, (vfloat4*)op);
    __builtin_nontemporal_store(hi, (vfloat4*)(op + 4));
}

__global__ __launch_bounds__(256, 4) void sample_sorted_u4(
    const float4* __restrict__ sorted, const __half* __restrict__ planes,
    float* __restrict__ out, int npts, int nb_q, int nb_r)
{
    sample_body(sorted, planes, out, npts, nb_q, nb_r, blockIdx.x, threadIdx.x);
}

// Diagnostic probe: identical work, run twice, output to d_ws scratch.
// Makes the sampler's duration and FETCH/WRITE counters visible in the
// top-5 dispatch table (2x dur clears the ~145us harness-fill threshold).
__global__ __launch_bounds__(256, 4) void sample_ws(
    const float4* __restrict__ sorted, const __half* __restrict__ planes,
    float* __restrict__ out, int npts, int nb_q, int nb_r)
{
    #pragma unroll 1
    for (int rep = 0; rep < 2; ++rep)
        sample_body(sorted, planes, out, npts, nb_q, nb_r, blockIdx.x, threadIdx.x);
}

// ---------------------------------------------------------------------------
// Fallback if d_ws is too small: sample directly from (C,H,W) fp32.
// ---------------------------------------------------------------------------
__global__ __launch_bounds__(256) void triplane_sample_chw(
    const float* __restrict__ x, const float* __restrict__ p0,
    const float* __restrict__ p1, const float* __restrict__ p2,
    float* __restrict__ out, int npts)
{
    int gid = blockIdx.x * 256 + threadIdx.x;
    int b = gid >> 5;
    int c = gid & 31;
    if (b >= npts) return;

    float c0 = x[b * 3 + 0], c1 = x[b * 3 + 1], c2 = x[b * 3 + 2];
    const float gxs[3] = { c0, c0, c1 };
    const float gys[3] = { c1, c2, c2 };
    const float* planes[3] = { p0, p1, p2 };

    float acc = 1.f;
    #pragma unroll
    for (int pl = 0; pl < 3; ++pl) {
        float ix = fmaf(gxs[pl], 255.5f, 255.5f);
        float iy = fmaf(gys[pl], 255.5f, 255.5f);
        float xf = floorf(ix), yf = floorf(iy);
        float wx = ix - xf,  wy = iy - yf;
        int x0 = min(max((int)xf, 0), RES - 2);
        int y0 = min(max((int)yf, 0), RES - 2);

        const float* base = planes[pl] + (size_t)c * HW + (size_t)y0 * RES + x0;
        float v00 = base[0], v01 = base[1], v10 = base[RES], v11 = base[RES + 1];

        float omx = 1.f - wx, omy = 1.f - wy;
        acc *= fmaf(v00, omx * omy, fmaf(v01, wx * omy,
               fmaf(v10, omx * wy, v11 * (wx * wy))));
    }
    out[(size_t)b * NCH + c] = acc;
}

extern "C" void kernel_launch(void* const* d_in, const int* in_sizes, int n_in,
                              void* d_out, int out_size, void* d_ws, size_t ws_size,
                              hipStream_t stream) {
    const float* x  = (const float*)d_in[0];
    const float* p0 = (const float*)d_in[1];
    const float* p1 = (const float*)d_in[2];
    const float* p2 = (const float*)d_in[3];
    float* out = (float*)d_out;
    int npts = in_sizes[0] / 3;

    // workspace layout
    size_t planes_bytes = (size_t)3 * PLANE_H_ELEMS * sizeof(__half);   // 50.3 MB
    size_t sorted_bytes = (size_t)npts * sizeof(float4);                // 32 MB
    size_t hist_bytes   = NBUCKETS * sizeof(unsigned);
    size_t need = planes_bytes + sorted_bytes + 2 * hist_bytes;

    if (ws_size >= need) {
        char* ws = (char*)d_ws;
        __half*   planes_h = (__half*)ws;
        float4*   sorted   = (float4*)(ws + planes_bytes);
        unsigned* hist     = (unsigned*)(ws + planes_bytes + sorted_bytes);
        unsigned* offs     = hist + NBUCKETS;

        zero_hist<<<NBUCKETS / 256, 256, 0, stream>>>(hist);
        fused_transpose_hist<<<HIST_BLOCKS + 3 * 4096, 256, 0, stream>>>(
            p0, p1, p2, (__half2*)planes_h, x, npts, hist);
        scan_kernel<<<1, 1024, 0, stream>>>(hist, offs);
        scatter_kernel<<<(npts + 255) / 256, 256, 0, stream>>>(x, npts, offs, sorted);

        int nchunks = (npts + 63) / 64;       // 64 points per block
        int nb_q = nchunks / 8, nb_r = nchunks & 7;
        sample_sorted_u4<<<nchunks, 256, 0, stream>>>(sorted, planes_h, out, npts, nb_q, nb_r);

        // Diagnostic probe (this round only): identical sampler x2 into scratch,
        // so its duration + FETCH/WRITE counters surface in the profile.
        size_t out_bytes = (size_t)out_size * sizeof(float);
        if (ws_size >= need + out_bytes) {
            float* out_ws = (float*)(ws + need);
            sample_ws<<<nchunks, 256, 0, stream>>>(sorted, planes_h, out_ws, npts, nb_q, nb_r);
        }
    } else {
        long long nthreads = (long long)npts * 32;
        int blocks = (int)((nthreads + 255) / 256);
        triplane_sample_chw<<<blocks, 256, 0, stream>>>(x, p0, p1, p2, out, npts);
    }
}

// Round 12
// 168.570 us; speedup vs baseline: 2.6521x; 2.6521x over previous
//
#include <hip/hip_runtime.h>
#include <hip/hip_fp16.h>

#define RES 512
#define NCH 32
#define HW (RES * RES)
#define PLANE_H_ELEMS (NCH * HW)     // half elements per transposed plane
#define NBUCKETS 4096                // 16x16x16 Morton voxel grid
#define NGRP 128                     // scatter groups (LDS-ranked sort)

typedef float vfloat4 __attribute__((ext_vector_type(4)));  // proven for NT STORE only

// ---------------------------------------------------------------------------
// Morton bucket helpers
// ---------------------------------------------------------------------------
__device__ __forceinline__ unsigned spread3(unsigned x) {
    x &= 0x3FF;
    x = (x | (x << 16)) & 0x030000FF;
    x = (x | (x <<  8)) & 0x0300F00F;
    x = (x | (x <<  4)) & 0x030C30C3;
    x = (x | (x <<  2)) & 0x09249249;
    return x;
}
__device__ __forceinline__ unsigned bucket_of(float c0, float c1, float c2) {
    int bx = min(max((int)(c0 * 16.f), 0), 15);
    int by = min(max((int)(c1 * 16.f), 0), 15);
    int bz = min(max((int)(c2 * 16.f), 0), 15);
    return spread3(bx) | (spread3(by) << 1) | (spread3(bz) << 2);
}

// ---------------------------------------------------------------------------
// prep: blocks [0,NGRP) build per-group histograms cnt[g][4096] (LDS atomics
// only, all entries written -> no pre-zero needed). Blocks [NGRP, NGRP+6144)
// transpose (C,H,W) fp32 -> (H,W,C) fp16, two 64-wide tiles per 512-thr block
// (tile body verbatim from the proven r10 transpose).
// ---------------------------------------------------------------------------
__global__ __launch_bounds__(512) void prep_kernel(
    const float* __restrict__ p0, const float* __restrict__ p1,
    const float* __restrict__ p2, __half2* __restrict__ dst_all,
    const float* __restrict__ x, int npts, unsigned* __restrict__ cnt)
{
    __shared__ char smem[17408];
    int blk = blockIdx.x;
    int t   = threadIdx.x;

    if (blk < NGRP) {
        // ---- per-group histogram ----
        unsigned* lh = (unsigned*)smem;
        for (int i = t; i < NBUCKETS; i += 512) lh[i] = 0;
        __syncthreads();
        int seg = (npts + NGRP - 1) / NGRP;
        int start = blk * seg;
        int end = min(npts, start + seg);
        for (int i = start + t; i < end; i += 512) {
            float c0 = x[3 * i + 0], c1 = x[3 * i + 1], c2 = x[3 * i + 2];
            atomicAdd(&lh[bucket_of(c0, c1, c2)], 1u);
        }
        __syncthreads();
        unsigned* dst = cnt + (size_t)blk * NBUCKETS;
        for (int i = t; i < NBUCKETS; i += 512) dst[i] = lh[i];   // coalesced dump
        return;
    }

    // ---- transpose: two tiles per block ----
    float* lds = (float*)smem;
    int tp   = blk - NGRP;
    int sub  = t >> 8;                 // 0 or 1: which tile
    int tt   = t & 255;
    int tile = tp * 2 + sub;           // 0..12287
    int plane = tile >> 12;
    int rem   = tile & 4095;
    int y     = rem >> 3;
    int xt    = (rem & 7) << 6;
    const float* src = (plane == 0) ? p0 : (plane == 1) ? p1 : p2;
    __half2* dst = dst_all + (size_t)plane * (PLANE_H_ELEMS / 2);
    float* myl = lds + sub * 2112;     // 64*33 floats per tile

    #pragma unroll
    for (int k = 0; k < 8; ++k) {
        int idx = tt + (k << 8);       // 0..2047
        int c   = idx >> 6;            // channel 0..31
        int xi  = idx & 63;            // x within tile
        myl[xi * 33 + c] = src[(size_t)c * HW + (size_t)y * RES + xt + xi];
    }
    __syncthreads();
    #pragma unroll
    for (int k = 0; k < 4; ++k) {
        int idx = tt + (k << 8);       // 0..1023
        int xi  = idx >> 4;            // x within tile
        int cp  = idx & 15;            // channel pair
        __half2 h = __halves2half2(__float2half_rn(myl[xi * 33 + 2 * cp]),
                                   __float2half_rn(myl[xi * 33 + 2 * cp + 1]));
        dst[((size_t)(y * RES + xt + xi)) * 16 + cp] = h;
    }
}

// ---------------------------------------------------------------------------
// group_prefix: one thread per bucket. Per-bucket exclusive prefix over the
// NGRP group counts (reads/writes coalesced across the wave: layout
// [g][bucket]) + per-bucket total.
// ---------------------------------------------------------------------------
__global__ __launch_bounds__(256) void group_prefix_kernel(
    const unsigned* __restrict__ cnt, unsigned* __restrict__ offs,
    unsigned* __restrict__ total)
{
    int bucket = blockIdx.x * 256 + threadIdx.x;   // 16 blocks x 256 = 4096
    unsigned run = 0;
    for (int g = 0; g < NGRP; ++g) {
        unsigned v = cnt[(size_t)g * NBUCKETS + bucket];
        offs[(size_t)g * NBUCKETS + bucket] = run;
        run += v;
    }
    total[bucket] = run;
}

// ---------------------------------------------------------------------------
// scan: exclusive scan of 4096 bucket totals -> base. (proven kernel)
// ---------------------------------------------------------------------------
__global__ __launch_bounds__(1024) void scan_kernel(
    const unsigned* __restrict__ hist, unsigned* __restrict__ offs)
{
    __shared__ unsigned sd[1024];
    int t = threadIdx.x;
    unsigned h0 = hist[4 * t + 0], h1 = hist[4 * t + 1];
    unsigned h2 = hist[4 * t + 2], h3 = hist[4 * t + 3];
    sd[t] = h0 + h1 + h2 + h3;
    __syncthreads();
    for (int d = 1; d < 1024; d <<= 1) {
        unsigned v = (t >= d) ? sd[t - d] : 0u;
        __syncthreads();
        sd[t] += v;
        __syncthreads();
    }
    unsigned excl = (t > 0) ? sd[t - 1] : 0u;
    offs[4 * t + 0] = excl;
    offs[4 * t + 1] = excl + h0;
    offs[4 * t + 2] = excl + h0 + h1;
    offs[4 * t + 3] = excl + h0 + h1 + h2;
}

// ---------------------------------------------------------------------------
// scatter_ranked: block g re-reads its segment; rank via LDS atomicAdd;
// pos = base[bucket] + offs[g][bucket] + rank. NO global atomics.
// ---------------------------------------------------------------------------
__global__ __launch_bounds__(512) void scatter_ranked_kernel(
    const float* __restrict__ x, int npts, const unsigned* __restrict__ base,
    const unsigned* __restrict__ offs, float4* __restrict__ sorted)
{
    __shared__ unsigned posb[NBUCKETS];
    __shared__ unsigned lcnt[NBUCKETS];
    int g = blockIdx.x, t = threadIdx.x;
    for (int i = t; i < NBUCKETS; i += 512) {
        posb[i] = base[i] + offs[(size_t)g * NBUCKETS + i];
        lcnt[i] = 0;
    }
    __syncthreads();
    int seg = (npts + NGRP - 1) / NGRP;
    int start = g * seg;
    int end = min(npts, start + seg);
    for (int i = start + t; i < end; i += 512) {
        float c0 = x[3 * i + 0], c1 = x[3 * i + 1], c2 = x[3 * i + 2];
        unsigned b = bucket_of(c0, c1, c2);
        unsigned r = atomicAdd(&lcnt[b], 1u);
        sorted[posb[b] + r] = make_float4(c0, c1, c2, __int_as_float(i));
    }
}

// ---------------------------------------------------------------------------
// fp16-pair decode + bilinear accumulate (proven math path).
// ---------------------------------------------------------------------------
__device__ __forceinline__ float2 dec2(unsigned u) {
    return __half22float2(__builtin_bit_cast(__half2, u));
}
__device__ __forceinline__ void bilerp2(float2& acc, unsigned c00, unsigned c01,
                                        unsigned c10, unsigned c11,
                                        float w00, float w01, float w10, float w11) {
    float2 a = dec2(c00), b = dec2(c01), c = dec2(c10), d = dec2(c11);
    float f0 = fmaf(a.x, w00, fmaf(b.x, w01, fmaf(c.x, w10, d.x * w11)));
    float f1 = fmaf(a.y, w00, fmaf(b.y, w01, fmaf(c.y, w10, d.y * w11)));
    acc.x *= f0; acc.y *= f1;
}

// ---------------------------------------------------------------------------
// Main sampler (verbatim r10, probe removed): 4 lanes/point, uint4 corner
// gathers, NT ext-vector stores. At the ~2.85 TB/s HBM write roofline.
// ---------------------------------------------------------------------------
__global__ __launch_bounds__(256, 4) void sample_sorted_u4(
    const float4* __restrict__ sorted, const __half* __restrict__ planes,
    float* __restrict__ out, int npts, int nb_q, int nb_r)
{
    int bid = blockIdx.x;
    int xcd = bid & 7;
    int j   = bid >> 3;
    int chunk = (xcd < nb_r ? xcd * (nb_q + 1) : nb_r * (nb_q + 1) + (xcd - nb_r) * nb_q) + j;

    int s = chunk * 64 + (threadIdx.x >> 2);   // 64 points per block
    int q = threadIdx.x & 3;                   // channel octet
    if (s >= npts) return;

    float4 p = sorted[s];
    int b = __float_as_int(p.w);               // original point index

    const float gxs[3] = { p.x, p.x, p.y };
    const float gys[3] = { p.y, p.z, p.z };

    const __half* base[3];
    float w00[3], w01[3], w10[3], w11[3];
    #pragma unroll
    for (int pl = 0; pl < 3; ++pl) {
        float ix = fmaf(gxs[pl], 255.5f, 255.5f);
        float iy = fmaf(gys[pl], 255.5f, 255.5f);
        float xf = floorf(ix), yf = floorf(iy);
        float wx = ix - xf,  wy = iy - yf;
        int x0 = min(max((int)xf, 0), RES - 2);
        int y0 = min(max((int)yf, 0), RES - 2);
        base[pl] = planes + (size_t)pl * PLANE_H_ELEMS
                 + (size_t)(y0 * RES + x0) * NCH + q * 8;
        float omx = 1.f - wx, omy = 1.f - wy;
        w00[pl] = omx * omy; w01[pl] = wx * omy;
        w10[pl] = omx * wy;  w11[pl] = wx * wy;
    }

    uint4 u00[3], u01[3], u10[3], u11[3];
    #pragma unroll
    for (int pl = 0; pl < 3; ++pl) {
        u00[pl] = *(const uint4*)(base[pl]);
        u01[pl] = *(const uint4*)(base[pl] + NCH);
        u10[pl] = *(const uint4*)(base[pl] + RES * NCH);
        u11[pl] = *(const uint4*)(base[pl] + RES * NCH + NCH);
    }

    float2 acc0 = {1.f, 1.f}, acc1 = {1.f, 1.f}, acc2 = {1.f, 1.f}, acc3 = {1.f, 1.f};
    #pragma unroll
    for (int pl = 0; pl < 3; ++pl) {
        bilerp2(acc0, u00[pl].x, u01[pl].x, u10[pl].x, u11[pl].x,
                w00[pl], w01[pl], w10[pl], w11[pl]);
        bilerp2(acc1, u00[pl].y, u01[pl].y, u10[pl].y, u11[pl].y,
                w00[pl], w01[pl], w10[pl], w11[pl]);
        bilerp2(acc2, u00[pl].z, u01[pl].z, u10[pl].z, u11[pl].z,
                w00[pl], w01[pl], w10[pl], w11[pl]);
        bilerp2(acc3, u00[pl].w, u01[pl].w, u10[pl].w, u11[pl].w,
                w00[pl], w01[pl], w10[pl], w11[pl]);
    }

    float* op = out + (size_t)b * NCH + q * 8;
    vfloat4 lo = { acc0.x, acc0.y, acc1.x, acc1.y };
    vfloat4 hi = { acc2.x, acc2.y, acc3.x, acc3.y };
    __builtin_nontemporal_store(lo, (vfloat4*)op);
    __builtin_nontemporal_store(hi, (vfloat4*)(op + 4));
}

// ---------------------------------------------------------------------------
// Fallback if d_ws is too small: sample directly from (C,H,W) fp32.
// ---------------------------------------------------------------------------
__global__ __launch_bounds__(256) void triplane_sample_chw(
    const float* __restrict__ x, const float* __restrict__ p0,
    const float* __restrict__ p1, const float* __restrict__ p2,
    float* __restrict__ out, int npts)
{
    int gid = blockIdx.x * 256 + threadIdx.x;
    int b = gid >> 5;
    int c = gid & 31;
    if (b >= npts) return;

    float c0 = x[b * 3 + 0], c1 = x[b * 3 + 1], c2 = x[b * 3 + 2];
    const float gxs[3] = { c0, c0, c1 };
    const float gys[3] = { c1, c2, c2 };
    const float* planes[3] = { p0, p1, p2 };

    float acc = 1.f;
    #pragma unroll
    for (int pl = 0; pl < 3; ++pl) {
        float ix = fmaf(gxs[pl], 255.5f, 255.5f);
        float iy = fmaf(gys[pl], 255.5f, 255.5f);
        float xf = floorf(ix), yf = floorf(iy);
        float wx = ix - xf,  wy = iy - yf;
        int x0 = min(max((int)xf, 0), RES - 2);
        int y0 = min(max((int)yf, 0), RES - 2);

        const float* base = planes[pl] + (size_t)c * HW + (size_t)y0 * RES + x0;
        float v00 = base[0], v01 = base[1], v10 = base[RES], v11 = base[RES + 1];

        float omx = 1.f - wx, omy = 1.f - wy;
        acc *= fmaf(v00, omx * omy, fmaf(v01, wx * omy,
               fmaf(v10, omx * wy, v11 * (wx * wy))));
    }
    out[(size_t)b * NCH + c] = acc;
}

extern "C" void kernel_launch(void* const* d_in, const int* in_sizes, int n_in,
                              void* d_out, int out_size, void* d_ws, size_t ws_size,
                              hipStream_t stream) {
    const float* x  = (const float*)d_in[0];
    const float* p0 = (const float*)d_in[1];
    const float* p1 = (const float*)d_in[2];
    const float* p2 = (const float*)d_in[3];
    float* out = (float*)d_out;
    int npts = in_sizes[0] / 3;

    // workspace layout
    size_t planes_bytes = (size_t)3 * PLANE_H_ELEMS * sizeof(__half);    // 50.3 MB
    size_t sorted_bytes = (size_t)npts * sizeof(float4);                 // 32 MB
    size_t cnt_bytes    = (size_t)NGRP * NBUCKETS * sizeof(unsigned);    // 2 MB
    size_t offs_bytes   = cnt_bytes;                                     // 2 MB
    size_t tot_bytes    = NBUCKETS * sizeof(unsigned);                   // 16 KB
    size_t need = planes_bytes + sorted_bytes + cnt_bytes + offs_bytes + 2 * tot_bytes;

    if (ws_size >= need) {
        char* ws = (char*)d_ws;
        __half*   planes_h = (__half*)ws;
        float4*   sorted   = (float4*)(ws + planes_bytes);
        unsigned* cnt      = (unsigned*)(ws + planes_bytes + sorted_bytes);
        unsigned* offs     = cnt + (size_t)NGRP * NBUCKETS;
        unsigned* total    = offs + (size_t)NGRP * NBUCKETS;
        unsigned* base     = total + NBUCKETS;

        prep_kernel<<<NGRP + 6144, 512, 0, stream>>>(p0, p1, p2,
                                                     (__half2*)planes_h, x, npts, cnt);
        group_prefix_kernel<<<NBUCKETS / 256, 256, 0, stream>>>(cnt, offs, total);
        scan_kernel<<<1, 1024, 0, stream>>>(total, base);
        scatter_ranked_kernel<<<NGRP, 512, 0, stream>>>(x, npts, base, offs, sorted);

        int nchunks = (npts + 63) / 64;       // 64 points per block
        int nb_q = nchunks / 8, nb_r = nchunks & 7;
        sample_sorted_u4<<<nchunks, 256, 0, stream>>>(sorted, planes_h, out, npts, nb_q, nb_r);
    } else {
        long long nthreads = (long long)npts * 32;
        int blocks = (int)((nthreads + 255) / 256);
        triplane_sample_chw<<<blocks, 256, 0, stream>>>(x, p0, p1, p2, out, npts);
    }
}